// Round 6
// baseline (766.690 us; speedup 1.0000x reference)
//
#include <hip/hip_runtime.h>
#include <hip/hip_cooperative_groups.h>
#include <stdint.h>

namespace cg = cooperative_groups;

#define D 128
#define BETA 0.40546510810816444f   // log(1.5)
#define TSTR 136                     // padded LDS row stride (bf16 elems)

#define NWG  128                     // round-5 fallback bucket passes
#define MAXB 256                     // fallback: 512-row buckets, N <= 131072

#define CGRID 512                    // cooperative grid (blocks)
#define CTHR  512                    // cooperative block size
#define BROWS 256                    // rows per bucket (coop path)
#define MAXB2 512                    // max buckets (coop): N <= 131072

typedef __bf16 bf16x8 __attribute__((ext_vector_type(8)));
typedef float f32x4 __attribute__((ext_vector_type(4)));

__device__ __forceinline__ uint16_t f2bf(float f) {
    union { float f; uint32_t i; } x; x.f = f;
    uint32_t r = (x.i + 0x7fffu + ((x.i >> 16) & 1u)) >> 16;
    return (uint16_t)r;
}
__device__ __forceinline__ float lo_f(uint32_t u) { return __uint_as_float(u << 16); }
__device__ __forceinline__ float hi_f(uint32_t u) { return __uint_as_float(u & 0xffff0000u); }
__device__ __forceinline__ uint32_t pack2(float x, float y) {
    return (uint32_t)f2bf(x) | ((uint32_t)f2bf(y) << 16);
}

// ============== cooperative mega-build: prep+cvt+bhist | scan | group | place
// One dispatch replaces four; grid.sync() (~µs) replaces dispatch gaps (~30µs).
// 256-row buckets; record x = (row&255)<<17 | col (needs N <= 131072).
__global__ __launch_bounds__(CTHR, 4) void k_build(
        const float* __restrict__ W, const float* __restrict__ w1,
        const float* __restrict__ w2, uint16_t* __restrict__ M1T,
        uint16_t* __restrict__ M2T,
        const float4* __restrict__ egoq, uint2* __restrict__ egobq, int nquads,
        const int* __restrict__ row, const int* __restrict__ col,
        const float* __restrict__ vals,
        int* __restrict__ cnt, int* __restrict__ partial,
        uint2* __restrict__ grouped, int* __restrict__ rowptr,
        uint2* __restrict__ rec, int E, int N, int nbuck) {
    __shared__ float imrow[4][D];     // prep
    __shared__ int h[MAXB2];          // bhist
    __shared__ int s[CTHR];           // scans
    __shared__ int lb[MAXB2];         // group bases
    __shared__ int lc2[MAXB2];        // group counts
    __shared__ int lh[BROWS];         // place row hist/offsets
    __shared__ int lcc[BROWS];        // place row counters
    __shared__ int ps[BROWS];         // place scan
    int t = threadIdx.x, bid = blockIdx.x, G = gridDim.x;
    cg::grid_group grid = cg::this_grid();

    // ---- phase 1a: prep (blocks 0..31, 4 k-rows each) ----
    if (bid < 32) {
        int q = t >> 7, n = t & 127;
        int k = bid * 4 + q;
        imrow[q][n] = (1.0f - BETA) + BETA * W[k * D + n];
        __syncthreads();
        float s1 = 0.f, s2 = 0.f;
        for (int j = 0; j < D; j++) {
            float im = imrow[q][j];
            s1 += im * w1[j * D + n];
            s2 += im * w2[j * D + n];
        }
        M1T[n * D + k] = f2bf(s1);
        M2T[n * D + k] = f2bf(s2);
    }
    // ---- phase 1b: cvt (grid-stride) ----
    for (int i = bid * CTHR + t; i < nquads; i += G * CTHR) {
        float4 v = egoq[i];
        uint2 o; o.x = pack2(v.x, v.y); o.y = pack2(v.z, v.w);
        egobq[i] = o;
    }
    // ---- phase 1c: bhist ----
    for (int b = t; b < nbuck; b += CTHR) h[b] = 0;
    __syncthreads();
    int chunk = (E + G - 1) / G;
    int ebeg = bid * chunk, eend = min(ebeg + chunk, E);
    for (int e = ebeg + t; e < eend; e += CTHR) {
        int r = row[e]; r = min(max(r, 0), N - 1);
        atomicAdd(&h[r >> 8], 1);
    }
    __syncthreads();
    for (int b = t; b < nbuck; b += CTHR) cnt[b * G + bid] = h[b];

    grid.sync();   // S1: all counts written

    // ---- phase 2: parallel exclusive scan of cnt[0..nbuck*G) ----
    int S = nbuck;                    // slice per block (G slices cover M exactly)
    {
        int base_i = bid * S;
        int v = (t < S) ? cnt[base_i + t] : 0;
        s[t] = v;
        __syncthreads();
        for (int d = 1; d < CTHR; d <<= 1) {
            int x = (t >= d) ? s[t - d] : 0;
            __syncthreads();
            s[t] += x;
            __syncthreads();
        }
        if (t < S) cnt[base_i + t] = s[t] - v;      // exclusive within slice
        if (t == CTHR - 1) partial[bid] = s[t];     // slice total
    }
    grid.sync();   // S2

    if (bid == 0) {
        int v = (t < G) ? partial[t] : 0;
        s[t] = v;
        __syncthreads();
        for (int d = 1; d < CTHR; d <<= 1) {
            int x = (t >= d) ? s[t - d] : 0;
            __syncthreads();
            s[t] += x;
            __syncthreads();
        }
        if (t < G) partial[t] = s[t] - v;           // exclusive slice offsets
        if (t == CTHR - 1) cnt[nbuck * G] = s[t];   // grand total (= E)
    }
    grid.sync();   // S3

    {
        int base_i = bid * S;
        int add = partial[bid];
        if (t < S) cnt[base_i + t] += add;
    }
    grid.sync();   // S4: cnt is now global exclusive offsets

    // ---- phase 3: group (per-WG private sequential bucket segments) ----
    for (int b = t; b < nbuck; b += CTHR) { lb[b] = cnt[b * G + bid]; lc2[b] = 0; }
    __syncthreads();
    for (int e = ebeg + t; e < eend; e += CTHR) {
        int r = row[e]; r = min(max(r, 0), N - 1);
        int c = col[e]; c = min(max(c, 0), N - 1);
        int b = r >> 8;
        int lp = atomicAdd(&lc2[b], 1);
        int pos = lb[b] + lp;
        pos = min(max(pos, 0), E - 1);
        uint2 g;
        g.x = ((uint32_t)(r & 255) << 17) | (uint32_t)c;
        g.y = __float_as_uint(vals[e]);
        grouped[pos] = g;
    }
    grid.sync();   // S5: grouped complete

    // ---- phase 4: place (one bucket per block; window ~65KB, L2-local) ----
    for (int b = bid; b < nbuck; b += G) {
        int pb = cnt[b * G], pe = cnt[(b + 1) * G];
        if (t < BROWS) { lh[t] = 0; lcc[t] = 0; }
        __syncthreads();
        for (int i = pb + t; i < pe; i += CTHR)
            atomicAdd(&lh[grouped[i].x >> 17], 1);
        __syncthreads();
        int v = (t < BROWS) ? lh[t] : 0;
        if (t < BROWS) ps[t] = v;
        __syncthreads();
        for (int d = 1; d < BROWS; d <<= 1) {
            int x = (t < BROWS && t >= d) ? ps[t - d] : 0;
            __syncthreads();
            if (t < BROWS) ps[t] += x;
            __syncthreads();
        }
        if (t < BROWS) lh[t] = ps[t] - v;           // exclusive row offsets
        __syncthreads();
        int rbase = b << 8;
        if (t < BROWS) {
            int r = rbase + t;
            if (r < N) rowptr[r] = pb + lh[t];
        }
        if (b == nbuck - 1 && t == 0) rowptr[N] = E;
        for (int i = pb + t; i < pe; i += CTHR) {
            uint2 g = grouped[i];
            int rl = (int)(g.x >> 17);
            int lp = atomicAdd(&lcc[rl], 1);
            int pos = pb + lh[rl] + lp;
            pos = min(max(pos, 0), E - 1);
            uint2 rv; rv.x = g.x & 0x1FFFFu; rv.y = g.y;
            rec[pos] = rv;
        }
        __syncthreads();
    }
}

// ================= legacy CSR build (N > 131072 fallback) ==================
__global__ void k_hist(const int* __restrict__ row, int* __restrict__ deg, int E, int N) {
    int e = blockIdx.x * blockDim.x + threadIdx.x;
    if (e < E) {
        int r = row[e]; r = min(max(r, 0), N - 1);
        atomicAdd(&deg[r], 1);
    }
}

__global__ void k_scan1(const int* __restrict__ deg, int* __restrict__ inc,
                        int* __restrict__ bsum, int n) {
    __shared__ int s[1024];
    int i = blockIdx.x * 1024 + threadIdx.x;
    int v = (i < n) ? deg[i] : 0;
    s[threadIdx.x] = v;
    __syncthreads();
    for (int d = 1; d < 1024; d <<= 1) {
        int t = (threadIdx.x >= (unsigned)d) ? s[threadIdx.x - d] : 0;
        __syncthreads();
        s[threadIdx.x] += t;
        __syncthreads();
    }
    if (i < n) inc[i] = s[threadIdx.x];
    if (threadIdx.x == 1023) bsum[blockIdx.x] = s[1023];
}

__global__ void k_scan2(const int* __restrict__ bsum, int* __restrict__ boff,
                        int nb, int* __restrict__ rowptr, int N) {
    int run = 0;
    for (int b = 0; b < nb; b++) { boff[b] = run; run += bsum[b]; }
    rowptr[N] = run;
}

__global__ void k_scan3(const int* __restrict__ deg, const int* __restrict__ boff,
                        int* __restrict__ rowptr, int* __restrict__ wp, int n) {
    int i = blockIdx.x * 1024 + threadIdx.x;
    if (i < n) {
        int ex = rowptr[i] - deg[i] + boff[blockIdx.x];
        rowptr[i] = ex;
        wp[i] = ex;
    }
}

__global__ void k_scatter(const int* __restrict__ row, const int* __restrict__ col,
                          const float* __restrict__ vals, int* __restrict__ wp,
                          uint2* __restrict__ rec, int E, int N) {
    int e = blockIdx.x * blockDim.x + threadIdx.x;
    if (e < E) {
        int r = row[e]; r = min(max(r, 0), N - 1);
        int pos = atomicAdd(&wp[r], 1);
        pos = min(max(pos, 0), E - 1);
        uint2 rv;
        rv.x = (uint32_t)col[e];
        rv.y = __float_as_uint(vals[e]);
        rec[pos] = rv;
    }
}

// ======== standalone prep/cvt (fallback paths) ========
__global__ void k_cvt(const float4* __restrict__ src, uint2* __restrict__ dst, int n) {
    int i = blockIdx.x * blockDim.x + threadIdx.x;
    if (i < n) {
        float4 v = src[i];
        uint2 o; o.x = pack2(v.x, v.y); o.y = pack2(v.z, v.w);
        dst[i] = o;
    }
}

__global__ void k_prep(const float* __restrict__ W, const float* __restrict__ w1,
                       const float* __restrict__ w2, uint16_t* __restrict__ M1T,
                       uint16_t* __restrict__ M2T) {
    int k = blockIdx.x, n = threadIdx.x;
    __shared__ float imrow[D];
    imrow[n] = (1.0f - BETA) + BETA * W[k * D + n];
    __syncthreads();
    float s1 = 0.f, s2 = 0.f;
    for (int j = 0; j < D; j++) {
        float im = imrow[j];
        s1 += im * w1[j * D + n];
        s2 += im * w2[j * D + n];
    }
    M1T[n * D + k] = f2bf(s1);
    M2T[n * D + k] = f2bf(s2);
}

// ============ round-5 non-cooperative bucket chain (fallback) ===============
__global__ __launch_bounds__(256) void k_front(
        const float* __restrict__ W, const float* __restrict__ w1,
        const float* __restrict__ w2, uint16_t* __restrict__ M1T,
        uint16_t* __restrict__ M2T,
        const float4* __restrict__ egoq, uint2* __restrict__ egobq, int nquads,
        const int* __restrict__ row, int* __restrict__ cnt,
        int E, int N, int nbuck, int cvtB) {
    __shared__ int h[MAXB];
    __shared__ float imrow[2][D];
    int tid = threadIdx.x;
    int bid = blockIdx.x;

    if (bid < 64) {
        int half = tid >> 7;
        int n = tid & 127;
        int k = bid * 2 + half;
        imrow[half][n] = (1.0f - BETA) + BETA * W[k * D + n];
        __syncthreads();
        float s1 = 0.f, s2 = 0.f;
        for (int j = 0; j < D; j++) {
            float im = imrow[half][j];
            s1 += im * w1[j * D + n];
            s2 += im * w2[j * D + n];
        }
        M1T[n * D + k] = f2bf(s1);
        M2T[n * D + k] = f2bf(s2);
        return;
    }
    if (bid < 64 + cvtB) {
        int i = (bid - 64) * 256 + tid;
        if (i < nquads) {
            float4 v = egoq[i];
            uint2 o; o.x = pack2(v.x, v.y); o.y = pack2(v.z, v.w);
            egobq[i] = o;
        }
        return;
    }
    int w = bid - 64 - cvtB;
    for (int b = tid; b < nbuck; b += 256) h[b] = 0;
    __syncthreads();
    int chunk = (E + NWG - 1) / NWG;
    int beg = w * chunk, end = min(beg + chunk, E);
    for (int e = beg + tid; e < end; e += 256) {
        int r = row[e]; r = min(max(r, 0), N - 1);
        atomicAdd(&h[r >> 9], 1);
    }
    __syncthreads();
    for (int b = tid; b < nbuck; b += 256) cnt[b * NWG + w] = h[b];
}

__global__ __launch_bounds__(1024) void k_scanWB(int* __restrict__ cnt, int M) {
    __shared__ int s[1024];
    int t = threadIdx.x;
    int per = (M + 1023) / 1024;
    int beg = t * per, end = min(beg + per, M);
    int sum = 0;
    for (int i = beg; i < end; i++) sum += cnt[i];
    s[t] = sum;
    __syncthreads();
    for (int d = 1; d < 1024; d <<= 1) {
        int v = (t >= d) ? s[t - d] : 0;
        __syncthreads();
        s[t] += v;
        __syncthreads();
    }
    int run = (t == 0) ? 0 : s[t - 1];
    for (int i = beg; i < end; i++) {
        int v = cnt[i];
        cnt[i] = run;
        run += v;
    }
    if (t == 1023) cnt[M] = s[1023];
}

__global__ __launch_bounds__(512) void k_group(const int* __restrict__ row,
                                               const int* __restrict__ col,
                                               const float* __restrict__ vals,
                                               const int* __restrict__ off,
                                               uint2* __restrict__ grouped,
                                               int E, int N, int nbuck) {
    __shared__ int lbase[MAXB];
    __shared__ int lcnt[MAXB];
    int w = blockIdx.x;
    for (int b = threadIdx.x; b < nbuck; b += 512) {
        lbase[b] = off[b * NWG + w];
        lcnt[b] = 0;
    }
    __syncthreads();
    int chunk = (E + NWG - 1) / NWG;
    int beg = w * chunk, end = min(beg + chunk, E);
    for (int e = beg + threadIdx.x; e < end; e += 512) {
        int r = row[e]; r = min(max(r, 0), N - 1);
        int c = col[e]; c = min(max(c, 0), N - 1);
        int b = r >> 9;
        int lp = atomicAdd(&lcnt[b], 1);
        int pos = lbase[b] + lp;
        pos = min(max(pos, 0), E - 1);
        uint2 g;
        g.x = ((uint32_t)(r & 511) << 17) | (uint32_t)c;
        g.y = __float_as_uint(vals[e]);
        grouped[pos] = g;
    }
}

__global__ __launch_bounds__(512) void k_place(const uint2* __restrict__ grouped,
                                               const int* __restrict__ off,
                                               int* __restrict__ rowptr,
                                               uint2* __restrict__ rec,
                                               int E, int N, int nbuck) {
    __shared__ int lh[512];
    __shared__ int lc[512];
    __shared__ int ps[512];
    int b = blockIdx.x;
    int t = threadIdx.x;
    int beg = off[b * NWG], end = off[(b + 1) * NWG];
    lh[t] = 0; lc[t] = 0;
    __syncthreads();
    for (int i = beg + t; i < end; i += 512)
        atomicAdd(&lh[grouped[i].x >> 17], 1);
    __syncthreads();
    ps[t] = lh[t];
    __syncthreads();
    for (int d = 1; d < 512; d <<= 1) {
        int v = (t >= d) ? ps[t - d] : 0;
        __syncthreads();
        ps[t] += v;
        __syncthreads();
    }
    int ex = (t == 0) ? 0 : ps[t - 1];
    lh[t] = ex;
    __syncthreads();
    int rbase = b << 9;
    int r = rbase + t;
    if (r < N) rowptr[r] = beg + lh[t];
    if (b == nbuck - 1 && t == 0) rowptr[N] = E;
    for (int i = beg + t; i < end; i += 512) {
        uint2 g = grouped[i];
        int rl = (int)(g.x >> 17);
        int lp = atomicAdd(&lc[rl], 1);
        int pos = beg + lh[rl] + lp;
        pos = min(max(pos, 0), E - 1);
        uint2 rv;
        rv.x = g.x & 0x1FFFFu;
        rv.y = g.y;
        rec[pos] = rv;
    }
}

// ======== shared phase-2: dual MFMA GEMM + leaky-relu epilogue (f32 out) ====
__device__ __forceinline__ void gemm_phase(
        const uint16_t* sT1, const uint16_t* sT2,
        const uint16_t* __restrict__ M1T, const uint16_t* __restrict__ M2T,
        const float* __restrict__ b1, const float* __restrict__ b2,
        float* __restrict__ out, int base, int wave, int lane, int N) {
    int l15 = lane & 15, quad = lane >> 4;
#pragma unroll
    for (int t = 0; t < 2; t++) {
        int tn = wave * 2 + t;
        f32x4 acc1 = {0.f, 0.f, 0.f, 0.f}, acc2 = {0.f, 0.f, 0.f, 0.f};
#pragma unroll
        for (int kb = 0; kb < 4; kb++) {
            int ko = kb * 32 + quad * 8;
            bf16x8 a1 = *(const bf16x8*)(sT1 + l15 * TSTR + ko);
            bf16x8 a2 = *(const bf16x8*)(sT2 + l15 * TSTR + ko);
            bf16x8 bb1 = *(const bf16x8*)(M1T + (tn * 16 + l15) * D + ko);
            bf16x8 bb2 = *(const bf16x8*)(M2T + (tn * 16 + l15) * D + ko);
            acc1 = __builtin_amdgcn_mfma_f32_16x16x32_bf16(a1, bb1, acc1, 0, 0, 0);
            acc2 = __builtin_amdgcn_mfma_f32_16x16x32_bf16(a2, bb2, acc2, 0, 0, 0);
        }
        int colo = tn * 16 + l15;
        float bbias1 = b1[colo], bbias2 = b2[colo];
#pragma unroll
        for (int r = 0; r < 4; r++) {
            int rowi = base + quad * 4 + r;
            if (rowi < N) {
                float v1 = acc1[r] + bbias1;
                v1 = (v1 >= 0.f) ? v1 : 0.01f * v1;
                float v2 = acc2[r] + bbias2;
                v2 = (v2 >= 0.f) ? v2 : 0.01f * v2;
                out[(size_t)rowi * D + colo] = v1 + v2;   // FLOAT32 output
            }
        }
    }
}

// ======== fast path: CSR gather (bf16 ego copy) -> LDS -> GEMM ========
__global__ __launch_bounds__(256) void k_fused(
        const int* __restrict__ rowptr, const uint2* __restrict__ rec,
        const uint32_t* __restrict__ egob,
        const float2* __restrict__ egf, const float2* __restrict__ hh,
        const uint16_t* __restrict__ M1T, const uint16_t* __restrict__ M2T,
        const float* __restrict__ b1, const float* __restrict__ b2,
        float* __restrict__ out, int N) {
    __shared__ __attribute__((aligned(16))) uint16_t sT1[16 * TSTR];
    __shared__ __attribute__((aligned(16))) uint16_t sT2[16 * TSTR];
    int tid = threadIdx.x;
    int wave = tid >> 6, lane = tid & 63;
    int base = blockIdx.x * 16;
    uint32_t* s1d = (uint32_t*)sT1;
    uint32_t* s2d = (uint32_t*)sT2;

#pragma unroll
    for (int i = 0; i < 4; i++) {
        int node = base + wave * 4 + i;
        float t1x = 0.f, t1y = 0.f, t2x = 0.f, t2y = 0.f;
        if (node < N) {
            int e0 = rowptr[node], e1 = rowptr[node + 1];
            float ax = 0.f, ay = 0.f, bx = 0.f, by = 0.f;
            int e = e0;
            for (; e + 8 <= e1; e += 8) {
                uint2 r0 = rec[e + 0], r1 = rec[e + 1], r2 = rec[e + 2], r3 = rec[e + 3];
                uint2 r4 = rec[e + 4], r5 = rec[e + 5], r6 = rec[e + 6], r7 = rec[e + 7];
                int c0 = min(max((int)r0.x, 0), N - 1);
                int c1 = min(max((int)r1.x, 0), N - 1);
                int c2 = min(max((int)r2.x, 0), N - 1);
                int c3 = min(max((int)r3.x, 0), N - 1);
                int c4 = min(max((int)r4.x, 0), N - 1);
                int c5 = min(max((int)r5.x, 0), N - 1);
                int c6 = min(max((int)r6.x, 0), N - 1);
                int c7 = min(max((int)r7.x, 0), N - 1);
                uint32_t u0 = egob[c0 * 64 + lane];
                uint32_t u1 = egob[c1 * 64 + lane];
                uint32_t u2 = egob[c2 * 64 + lane];
                uint32_t u3 = egob[c3 * 64 + lane];
                uint32_t u4 = egob[c4 * 64 + lane];
                uint32_t u5 = egob[c5 * 64 + lane];
                uint32_t u6 = egob[c6 * 64 + lane];
                uint32_t u7 = egob[c7 * 64 + lane];
                float v0 = __uint_as_float(r0.y), v1 = __uint_as_float(r1.y);
                float v2 = __uint_as_float(r2.y), v3 = __uint_as_float(r3.y);
                float v4 = __uint_as_float(r4.y), v5 = __uint_as_float(r5.y);
                float v6 = __uint_as_float(r6.y), v7 = __uint_as_float(r7.y);
                ax += v0 * lo_f(u0); ay += v0 * hi_f(u0);
                bx += v1 * lo_f(u1); by += v1 * hi_f(u1);
                ax += v2 * lo_f(u2); ay += v2 * hi_f(u2);
                bx += v3 * lo_f(u3); by += v3 * hi_f(u3);
                ax += v4 * lo_f(u4); ay += v4 * hi_f(u4);
                bx += v5 * lo_f(u5); by += v5 * hi_f(u5);
                ax += v6 * lo_f(u6); ay += v6 * hi_f(u6);
                bx += v7 * lo_f(u7); by += v7 * hi_f(u7);
            }
            if (e < e1) {
                int last = e1 - 1;
                uint2 rr[8];
#pragma unroll
                for (int k = 0; k < 8; k++) {
                    int idx = e + k;
                    rr[k] = rec[(idx <= last) ? idx : last];
                }
                uint32_t uu[8];
#pragma unroll
                for (int k = 0; k < 8; k++) {
                    int c = min(max((int)rr[k].x, 0), N - 1);
                    uu[k] = egob[c * 64 + lane];
                }
#pragma unroll
                for (int k = 0; k < 8; k++) {
                    float v = (e + k < e1) ? __uint_as_float(rr[k].y) : 0.f;
                    if (k & 1) { bx += v * lo_f(uu[k]); by += v * hi_f(uu[k]); }
                    else       { ax += v * lo_f(uu[k]); ay += v * hi_f(uu[k]); }
                }
            }
            ax += bx; ay += by;
            float2 se = egf[node * 64 + lane];
            float2 sh = hh[node * 64 + lane];
            t1x = 0.9f * (se.x + ax) + 0.1f * sh.x;
            t1y = 0.9f * (se.y + ay) + 0.1f * sh.y;
            t2x = 0.9f * (se.x * ax) + 0.1f * sh.x;
            t2y = 0.9f * (se.y * ay) + 0.1f * sh.y;
        }
        int r = wave * 4 + i;
        s1d[r * (TSTR / 2) + lane] = pack2(t1x, t1y);
        s2d[r * (TSTR / 2) + lane] = pack2(t2x, t2y);
    }
    __syncthreads();
    gemm_phase(sT1, sT2, M1T, M2T, b1, b2, out, base, wave, lane, N);
}

// ======== fallback path (tiny ws): f32 side accumulated in-place in d_out ====
__global__ __launch_bounds__(256) void k_coo_side(
        const int* __restrict__ row, const int* __restrict__ col,
        const float* __restrict__ vals, const float2* __restrict__ egf,
        float* __restrict__ sideF, int E, int N) {
    long long t = (long long)blockIdx.x * blockDim.x + threadIdx.x;
    int e = (int)(t >> 6), l = (int)(t & 63);
    if (e >= E) return;
    int c = col[e]; c = min(max(c, 0), N - 1);
    int r = row[e]; r = min(max(r, 0), N - 1);
    float v = vals[e];
    float2 u = egf[c * 64 + l];
    atomicAdd(&sideF[r * D + 2 * l],     v * u.x);
    atomicAdd(&sideF[r * D + 2 * l + 1], v * u.y);
}

__global__ __launch_bounds__(256) void k_fused2(
        const float2* __restrict__ egf, const float2* __restrict__ hh,
        const uint16_t* __restrict__ M1T, const uint16_t* __restrict__ M2T,
        const float* __restrict__ b1, const float* __restrict__ b2,
        float* __restrict__ out, int N) {
    __shared__ __attribute__((aligned(16))) uint16_t sT1[16 * TSTR];
    __shared__ __attribute__((aligned(16))) uint16_t sT2[16 * TSTR];
    int tid = threadIdx.x;
    int wave = tid >> 6, lane = tid & 63;
    int base = blockIdx.x * 16;
    const float2* sd = (const float2*)out;
    uint32_t* s1d = (uint32_t*)sT1;
    uint32_t* s2d = (uint32_t*)sT2;

#pragma unroll
    for (int i = 0; i < 4; i++) {
        int node = base + wave * 4 + i;
        float t1x = 0.f, t1y = 0.f, t2x = 0.f, t2y = 0.f;
        if (node < N) {
            float2 us = sd[node * 64 + lane];
            float2 se = egf[node * 64 + lane];
            float2 sh = hh[node * 64 + lane];
            t1x = 0.9f * (se.x + us.x) + 0.1f * sh.x;
            t1y = 0.9f * (se.y + us.y) + 0.1f * sh.y;
            t2x = 0.9f * (se.x * us.x) + 0.1f * sh.x;
            t2y = 0.9f * (se.y * us.y) + 0.1f * sh.y;
        }
        int r = wave * 4 + i;
        s1d[r * (TSTR / 2) + lane] = pack2(t1x, t1y);
        s2d[r * (TSTR / 2) + lane] = pack2(t2x, t2y);
    }
    __syncthreads();
    gemm_phase(sT1, sT2, M1T, M2T, b1, b2, out, base, wave, lane, N);
}

extern "C" void kernel_launch(void* const* d_in, const int* in_sizes, int n_in,
                              void* d_out, int out_size, void* d_ws, size_t ws_size,
                              hipStream_t stream) {
    const float* ego  = (const float*)d_in[0];
    const float* h0   = (const float*)d_in[1];
    const float* vals = (const float*)d_in[2];
    const float* W    = (const float*)d_in[3];
    const float* w1   = (const float*)d_in[4];
    const float* b1   = (const float*)d_in[5];
    const float* w2   = (const float*)d_in[6];
    const float* b2   = (const float*)d_in[7];
    const int* row = (const int*)d_in[8];
    const int* col = (const int*)d_in[9];
    int N = in_sizes[0] / D;
    int E = in_sizes[2];

    int nbuck2 = (N + 255) >> 8;                  // coop path: 256-row buckets
    size_t cnt_elems = (size_t)nbuck2 * CGRID + 2;
    if (cnt_elems < (size_t)MAXB * NWG + 1) cnt_elems = (size_t)MAXB * NWG + 1;

    char* p = (char*)d_ws;
    auto alloc = [&](size_t bytes) -> char* {
        char* q = p;
        p += (bytes + 511) & ~(size_t)511;
        return q;
    };
    uint16_t* M1T    = (uint16_t*)alloc(D * D * 2);
    uint16_t* M2T    = (uint16_t*)alloc(D * D * 2);
    uint32_t* egob   = (uint32_t*)alloc((size_t)N * 64 * 4);
    int*      deg    = (int*)alloc((size_t)N * 4);
    int*      rowptr = (int*)alloc((size_t)(N + 1) * 4);
    int*      wp     = (int*)alloc((size_t)N * 4);
    int*      bsum   = (int*)alloc(1024 * 4);
    int*      boff   = (int*)alloc(1024 * 4);
    int*      partial= (int*)alloc(CGRID * 4);
    int*      cnt    = (int*)alloc(cnt_elems * 4);
    uint2*    rec    = (uint2*)alloc((size_t)E * 8);
    size_t need_fast = (size_t)(p - (char*)d_ws);

    // one-time capability probe for the cooperative mega-build
    static int coop_state = 0;   // 0=unknown, 1=ok, -1=unavailable
    if (coop_state == 0) {
        int maxb = 0;
        hipError_t oe = hipOccupancyMaxActiveBlocksPerMultiprocessor(&maxb, k_build, CTHR, 0);
        int cus = 0;
        hipDeviceProp_t prop;
        if (hipGetDeviceProperties(&prop, 0) == hipSuccess) cus = prop.multiProcessorCount;
        coop_state = (oe == hipSuccess && cus > 0 && maxb * cus >= CGRID) ? 1 : -1;
    }

    if (ws_size >= need_fast) {
        int nquads = N * 32;
        bool done_build = false;

        bool coop_ok = (coop_state == 1) && (nbuck2 <= MAXB2) &&
                       ((size_t)out_size * 4 >= (size_t)E * 8);
        if (coop_ok) {
            const float4* egoq = (const float4*)ego;
            uint2* egobq = (uint2*)egob;
            uint2* groupedp = (uint2*)d_out;
            void* args[] = {
                (void*)&W, (void*)&w1, (void*)&w2, (void*)&M1T, (void*)&M2T,
                (void*)&egoq, (void*)&egobq, (void*)&nquads,
                (void*)&row, (void*)&col, (void*)&vals,
                (void*)&cnt, (void*)&partial, (void*)&groupedp,
                (void*)&rowptr, (void*)&rec, (void*)&E, (void*)&N, (void*)&nbuck2
            };
            hipError_t le = hipLaunchCooperativeKernel(
                (const void*)k_build, dim3(CGRID), dim3(CTHR), args, 0, stream);
            if (le == hipSuccess) done_build = true;
            else coop_state = -1;    // don't retry a failing path
        }

        if (!done_build) {
            int nbuck = (N + 511) >> 9;
            bool bucket_ok = (nbuck <= MAXB) && ((size_t)out_size * 4 >= (size_t)E * 8)
                             && ((N & 1) == 0);
            if (bucket_ok) {
                int cvtB = (nquads + 255) / 256;
                int M = nbuck * NWG;
                k_front<<<64 + cvtB + NWG, 256, 0, stream>>>(
                    W, w1, w2, M1T, M2T,
                    (const float4*)ego, (uint2*)egob, nquads,
                    row, cnt, E, N, nbuck, cvtB);
                k_scanWB<<<1, 1024, 0, stream>>>(cnt, M);
                k_group<<<NWG, 512, 0, stream>>>(row, col, vals, cnt,
                                                 (uint2*)d_out, E, N, nbuck);
                k_place<<<nbuck, 512, 0, stream>>>((const uint2*)d_out, cnt,
                                                   rowptr, rec, E, N, nbuck);
            } else {
                k_prep<<<D, D, 0, stream>>>(W, w1, w2, M1T, M2T);
                k_cvt<<<(nquads + 255) / 256, 256, 0, stream>>>((const float4*)ego,
                                                                (uint2*)egob, nquads);
                hipMemsetAsync(deg, 0, (size_t)N * 4, stream);
                int nb = (N + 1023) / 1024;
                k_hist<<<(E + 255) / 256, 256, 0, stream>>>(row, deg, E, N);
                k_scan1<<<nb, 1024, 0, stream>>>(deg, rowptr, bsum, N);
                k_scan2<<<1, 1, 0, stream>>>(bsum, boff, nb, rowptr, N);
                k_scan3<<<nb, 1024, 0, stream>>>(deg, boff, rowptr, wp, N);
                k_scatter<<<(E + 255) / 256, 256, 0, stream>>>(row, col, vals, wp,
                                                               rec, E, N);
            }
        }

        int nblocks = (N + 15) / 16;
        k_fused<<<nblocks, 256, 0, stream>>>(rowptr, rec, egob,
                                             (const float2*)ego, (const float2*)h0,
                                             M1T, M2T, b1, b2, (float*)d_out, N);
    } else {
        k_prep<<<D, D, 0, stream>>>(W, w1, w2, M1T, M2T);
        hipMemsetAsync(d_out, 0, (size_t)out_size * 4, stream);
        long long tthr = (long long)E * 64;
        int blocks = (int)((tthr + 255) / 256);
        k_coo_side<<<blocks, 256, 0, stream>>>(row, col, vals, (const float2*)ego,
                                               (float*)d_out, E, N);
        int nblocks = (N + 15) / 16;
        k_fused2<<<nblocks, 256, 0, stream>>>((const float2*)ego, (const float2*)h0,
                                              M1T, M2T, b1, b2, (float*)d_out, N);
    }
}

// Round 7
// 475.608 us; speedup vs baseline: 1.6120x; 1.6120x over previous
//
#include <hip/hip_runtime.h>
#include <stdint.h>

#define D 128
#define BETA 0.40546510810816444f   // log(1.5)
#define TSTR 136                     // padded LDS row stride (bf16 elems)

#define NWG  128                     // legacy fallback bucket passes
#define MAXB 256                     // legacy: 512-row buckets, N <= 131072

#define NWG2 256                     // group/bhist workgroups (full machine)
#define BROWS 256                    // rows per bucket
#define MAXB2 512                    // max buckets: N <= 131072

typedef __bf16 bf16x8 __attribute__((ext_vector_type(8)));
typedef float f32x4 __attribute__((ext_vector_type(4)));

__device__ __forceinline__ uint16_t f2bf(float f) {
    union { float f; uint32_t i; } x; x.f = f;
    uint32_t r = (x.i + 0x7fffu + ((x.i >> 16) & 1u)) >> 16;
    return (uint16_t)r;
}
__device__ __forceinline__ float lo_f(uint32_t u) { return __uint_as_float(u << 16); }
__device__ __forceinline__ float hi_f(uint32_t u) { return __uint_as_float(u & 0xffff0000u); }
__device__ __forceinline__ uint32_t pack2(float x, float y) {
    return (uint32_t)f2bf(x) | ((uint32_t)f2bf(y) << 16);
}

// ================= legacy CSR build (N > 131072 fallback) ==================
__global__ void k_hist(const int* __restrict__ row, int* __restrict__ deg, int E, int N) {
    int e = blockIdx.x * blockDim.x + threadIdx.x;
    if (e < E) {
        int r = row[e]; r = min(max(r, 0), N - 1);
        atomicAdd(&deg[r], 1);
    }
}

__global__ void k_scan1(const int* __restrict__ deg, int* __restrict__ inc,
                        int* __restrict__ bsum, int n) {
    __shared__ int s[1024];
    int i = blockIdx.x * 1024 + threadIdx.x;
    int v = (i < n) ? deg[i] : 0;
    s[threadIdx.x] = v;
    __syncthreads();
    for (int d = 1; d < 1024; d <<= 1) {
        int t = (threadIdx.x >= (unsigned)d) ? s[threadIdx.x - d] : 0;
        __syncthreads();
        s[threadIdx.x] += t;
        __syncthreads();
    }
    if (i < n) inc[i] = s[threadIdx.x];
    if (threadIdx.x == 1023) bsum[blockIdx.x] = s[1023];
}

__global__ void k_scan2(const int* __restrict__ bsum, int* __restrict__ boff,
                        int nb, int* __restrict__ rowptr, int N) {
    int run = 0;
    for (int b = 0; b < nb; b++) { boff[b] = run; run += bsum[b]; }
    rowptr[N] = run;
}

__global__ void k_scan3(const int* __restrict__ deg, const int* __restrict__ boff,
                        int* __restrict__ rowptr, int* __restrict__ wp, int n) {
    int i = blockIdx.x * 1024 + threadIdx.x;
    if (i < n) {
        int ex = rowptr[i] - deg[i] + boff[blockIdx.x];
        rowptr[i] = ex;
        wp[i] = ex;
    }
}

__global__ void k_scatter(const int* __restrict__ row, const int* __restrict__ col,
                          const float* __restrict__ vals, int* __restrict__ wp,
                          uint2* __restrict__ rec, int E, int N) {
    int e = blockIdx.x * blockDim.x + threadIdx.x;
    if (e < E) {
        int r = row[e]; r = min(max(r, 0), N - 1);
        int pos = atomicAdd(&wp[r], 1);
        pos = min(max(pos, 0), E - 1);
        uint2 rv;
        rv.x = (uint32_t)col[e];
        rv.y = __float_as_uint(vals[e]);
        rec[pos] = rv;
    }
}

// ======== standalone prep/cvt (fallback paths) ========
__global__ void k_cvt(const float4* __restrict__ src, uint2* __restrict__ dst, int n) {
    int i = blockIdx.x * blockDim.x + threadIdx.x;
    if (i < n) {
        float4 v = src[i];
        uint2 o; o.x = pack2(v.x, v.y); o.y = pack2(v.z, v.w);
        dst[i] = o;
    }
}

__global__ void k_prep(const float* __restrict__ W, const float* __restrict__ w1,
                       const float* __restrict__ w2, uint16_t* __restrict__ M1T,
                       uint16_t* __restrict__ M2T) {
    int k = blockIdx.x, n = threadIdx.x;
    __shared__ float imrow[D];
    imrow[n] = (1.0f - BETA) + BETA * W[k * D + n];
    __syncthreads();
    float s1 = 0.f, s2 = 0.f;
    for (int j = 0; j < D; j++) {
        float im = imrow[j];
        s1 += im * w1[j * D + n];
        s2 += im * w2[j * D + n];
    }
    M1T[n * D + k] = f2bf(s1);
    M2T[n * D + k] = f2bf(s2);
}

// ============ fused front: prep (0..63) + cvt + bhist (256 WGs) =============
__global__ __launch_bounds__(256) void k_front(
        const float* __restrict__ W, const float* __restrict__ w1,
        const float* __restrict__ w2, uint16_t* __restrict__ M1T,
        uint16_t* __restrict__ M2T,
        const float4* __restrict__ egoq, uint2* __restrict__ egobq, int nquads,
        const int* __restrict__ row, int* __restrict__ cnt,
        int E, int N, int nbuck, int cvtB) {
    __shared__ int h[MAXB2];
    __shared__ float imrow[2][D];
    int tid = threadIdx.x;
    int bid = blockIdx.x;

    if (bid < 64) {
        // ---- prep role: 2 k-rows per block ----
        int half = tid >> 7;
        int n = tid & 127;
        int k = bid * 2 + half;
        imrow[half][n] = (1.0f - BETA) + BETA * W[k * D + n];
        __syncthreads();
        float s1 = 0.f, s2 = 0.f;
        for (int j = 0; j < D; j++) {
            float im = imrow[half][j];
            s1 += im * w1[j * D + n];
            s2 += im * w2[j * D + n];
        }
        M1T[n * D + k] = f2bf(s1);
        M2T[n * D + k] = f2bf(s2);
        return;
    }
    if (bid < 64 + cvtB) {
        // ---- cvt role ----
        int i = (bid - 64) * 256 + tid;
        if (i < nquads) {
            float4 v = egoq[i];
            uint2 o; o.x = pack2(v.x, v.y); o.y = pack2(v.z, v.w);
            egobq[i] = o;
        }
        return;
    }
    // ---- bhist role (256 WGs, 256-row buckets) ----
    int w = bid - 64 - cvtB;
    for (int b = tid; b < nbuck; b += 256) h[b] = 0;
    __syncthreads();
    int chunk = (E + NWG2 - 1) / NWG2;
    int beg = w * chunk, end = min(beg + chunk, E);
    for (int e = beg + tid; e < end; e += 256) {
        int r = row[e]; r = min(max(r, 0), N - 1);
        atomicAdd(&h[r >> 8], 1);
    }
    __syncthreads();
    for (int b = tid; b < nbuck; b += 256) cnt[b * NWG2 + w] = h[b];
}

// ============ bucket-base scan: one small kernel, full parallel =============
// Thread t sums bucket t's 256 contiguous counts (int4), then 512-wide LDS
// ladder gives exclusive bucket bases. bbase[nbuck] = E.
__global__ __launch_bounds__(512) void k_btop(const int* __restrict__ cnt,
                                              int* __restrict__ bbase, int nbuck) {
    __shared__ int s[512];
    int t = threadIdx.x;
    int sum = 0;
    if (t < nbuck) {
        const int4* p4 = (const int4*)(cnt + t * NWG2);
#pragma unroll 4
        for (int i = 0; i < NWG2 / 4; i++) {
            int4 v = p4[i];
            sum += v.x + v.y + v.z + v.w;
        }
    }
    s[t] = sum;
    __syncthreads();
    for (int d = 1; d < 512; d <<= 1) {
        int x = (t >= d) ? s[t - d] : 0;
        __syncthreads();
        s[t] += x;
        __syncthreads();
    }
    if (t < nbuck) bbase[t] = s[t] - sum;   // exclusive
    if (t == 511) bbase[nbuck] = s[511];    // total (= E)
}

// ============ group: 256 WGs x 512 thr; per-WG private bucket segments ======
// Prelude computes lbase[b] = bbase[b] + sum_{w'<w} cnt[b][w'] from the
// L2-hot cnt matrix (replaces the global scan over nbuck*NWG2 entries).
// Record: x = (row&255)<<17 | col (needs N <= 131072).
__global__ __launch_bounds__(512) void k_group2(const int* __restrict__ row,
                                                const int* __restrict__ col,
                                                const float* __restrict__ vals,
                                                const int* __restrict__ cnt,
                                                const int* __restrict__ bbase,
                                                uint2* __restrict__ grouped,
                                                int E, int N, int nbuck) {
    __shared__ int lbase[MAXB2];
    __shared__ int lcnt[MAXB2];
    int t = threadIdx.x;
    int w = blockIdx.x;
    for (int b = t; b < nbuck; b += 512) {
        const int* cr = cnt + b * NWG2;
        int off = bbase[b];
        for (int w2 = 0; w2 < w; w2++) off += cr[w2];
        lbase[b] = off;
        lcnt[b] = 0;
    }
    __syncthreads();
    int chunk = (E + NWG2 - 1) / NWG2;
    int beg = w * chunk, end = min(beg + chunk, E);
    for (int e = beg + t; e < end; e += 512) {
        int r = row[e]; r = min(max(r, 0), N - 1);
        int c = col[e]; c = min(max(c, 0), N - 1);
        int b = r >> 8;
        int lp = atomicAdd(&lcnt[b], 1);
        int pos = lbase[b] + lp;
        pos = min(max(pos, 0), E - 1);
        uint2 g;
        g.x = ((uint32_t)(r & 255) << 17) | (uint32_t)c;
        g.y = __float_as_uint(vals[e]);
        grouped[pos] = g;
    }
}

// ============ place: one block per 256-row bucket (~391 blocks) =============
__global__ __launch_bounds__(512) void k_place2(const uint2* __restrict__ grouped,
                                                const int* __restrict__ bbase,
                                                int* __restrict__ rowptr,
                                                uint2* __restrict__ rec,
                                                int E, int N, int nbuck) {
    __shared__ int lh[BROWS];
    __shared__ int lcc[BROWS];
    __shared__ int ps[BROWS];
    int b = blockIdx.x;
    int t = threadIdx.x;
    int pb = bbase[b], pe = bbase[b + 1];
    if (t < BROWS) { lh[t] = 0; lcc[t] = 0; }
    __syncthreads();
    for (int i = pb + t; i < pe; i += 512)
        atomicAdd(&lh[grouped[i].x >> 17], 1);
    __syncthreads();
    int v = (t < BROWS) ? lh[t] : 0;
    if (t < BROWS) ps[t] = v;
    __syncthreads();
    for (int d = 1; d < BROWS; d <<= 1) {
        int x = (t < BROWS && t >= d) ? ps[t - d] : 0;
        __syncthreads();
        if (t < BROWS) ps[t] += x;
        __syncthreads();
    }
    if (t < BROWS) lh[t] = ps[t] - v;           // exclusive row offsets
    __syncthreads();
    int rbase = b << 8;
    if (t < BROWS) {
        int r = rbase + t;
        if (r < N) rowptr[r] = pb + lh[t];
    }
    if (b == nbuck - 1 && t == 0) rowptr[N] = E;
    for (int i = pb + t; i < pe; i += 512) {
        uint2 g = grouped[i];
        int rl = (int)(g.x >> 17);
        int lp = atomicAdd(&lcc[rl], 1);
        int pos = pb + lh[rl] + lp;
        pos = min(max(pos, 0), E - 1);
        uint2 rv; rv.x = g.x & 0x1FFFFu; rv.y = g.y;
        rec[pos] = rv;
    }
}

// ======== shared phase-2: dual MFMA GEMM + leaky-relu epilogue (f32 out) ====
__device__ __forceinline__ void gemm_phase(
        const uint16_t* sT1, const uint16_t* sT2,
        const uint16_t* __restrict__ M1T, const uint16_t* __restrict__ M2T,
        const float* __restrict__ b1, const float* __restrict__ b2,
        float* __restrict__ out, int base, int wave, int lane, int N) {
    int l15 = lane & 15, quad = lane >> 4;
#pragma unroll
    for (int t = 0; t < 2; t++) {
        int tn = wave * 2 + t;
        f32x4 acc1 = {0.f, 0.f, 0.f, 0.f}, acc2 = {0.f, 0.f, 0.f, 0.f};
#pragma unroll
        for (int kb = 0; kb < 4; kb++) {
            int ko = kb * 32 + quad * 8;
            bf16x8 a1 = *(const bf16x8*)(sT1 + l15 * TSTR + ko);
            bf16x8 a2 = *(const bf16x8*)(sT2 + l15 * TSTR + ko);
            bf16x8 bb1 = *(const bf16x8*)(M1T + (tn * 16 + l15) * D + ko);
            bf16x8 bb2 = *(const bf16x8*)(M2T + (tn * 16 + l15) * D + ko);
            acc1 = __builtin_amdgcn_mfma_f32_16x16x32_bf16(a1, bb1, acc1, 0, 0, 0);
            acc2 = __builtin_amdgcn_mfma_f32_16x16x32_bf16(a2, bb2, acc2, 0, 0, 0);
        }
        int colo = tn * 16 + l15;
        float bbias1 = b1[colo], bbias2 = b2[colo];
#pragma unroll
        for (int r = 0; r < 4; r++) {
            int rowi = base + quad * 4 + r;
            if (rowi < N) {
                float v1 = acc1[r] + bbias1;
                v1 = (v1 >= 0.f) ? v1 : 0.01f * v1;
                float v2 = acc2[r] + bbias2;
                v2 = (v2 >= 0.f) ? v2 : 0.01f * v2;
                out[(size_t)rowi * D + colo] = v1 + v2;   // FLOAT32 output
            }
        }
    }
}

// ======== fast path: CSR gather (bf16 ego copy) -> LDS -> GEMM ========
__global__ __launch_bounds__(256) void k_fused(
        const int* __restrict__ rowptr, const uint2* __restrict__ rec,
        const uint32_t* __restrict__ egob,
        const float2* __restrict__ egf, const float2* __restrict__ hh,
        const uint16_t* __restrict__ M1T, const uint16_t* __restrict__ M2T,
        const float* __restrict__ b1, const float* __restrict__ b2,
        float* __restrict__ out, int N) {
    __shared__ __attribute__((aligned(16))) uint16_t sT1[16 * TSTR];
    __shared__ __attribute__((aligned(16))) uint16_t sT2[16 * TSTR];
    int tid = threadIdx.x;
    int wave = tid >> 6, lane = tid & 63;
    int base = blockIdx.x * 16;
    uint32_t* s1d = (uint32_t*)sT1;
    uint32_t* s2d = (uint32_t*)sT2;

#pragma unroll
    for (int i = 0; i < 4; i++) {
        int node = base + wave * 4 + i;
        float t1x = 0.f, t1y = 0.f, t2x = 0.f, t2y = 0.f;
        if (node < N) {
            int e0 = rowptr[node], e1 = rowptr[node + 1];
            float ax = 0.f, ay = 0.f, bx = 0.f, by = 0.f;
            int e = e0;
            for (; e + 8 <= e1; e += 8) {
                uint2 r0 = rec[e + 0], r1 = rec[e + 1], r2 = rec[e + 2], r3 = rec[e + 3];
                uint2 r4 = rec[e + 4], r5 = rec[e + 5], r6 = rec[e + 6], r7 = rec[e + 7];
                int c0 = min(max((int)r0.x, 0), N - 1);
                int c1 = min(max((int)r1.x, 0), N - 1);
                int c2 = min(max((int)r2.x, 0), N - 1);
                int c3 = min(max((int)r3.x, 0), N - 1);
                int c4 = min(max((int)r4.x, 0), N - 1);
                int c5 = min(max((int)r5.x, 0), N - 1);
                int c6 = min(max((int)r6.x, 0), N - 1);
                int c7 = min(max((int)r7.x, 0), N - 1);
                uint32_t u0 = egob[c0 * 64 + lane];
                uint32_t u1 = egob[c1 * 64 + lane];
                uint32_t u2 = egob[c2 * 64 + lane];
                uint32_t u3 = egob[c3 * 64 + lane];
                uint32_t u4 = egob[c4 * 64 + lane];
                uint32_t u5 = egob[c5 * 64 + lane];
                uint32_t u6 = egob[c6 * 64 + lane];
                uint32_t u7 = egob[c7 * 64 + lane];
                float v0 = __uint_as_float(r0.y), v1 = __uint_as_float(r1.y);
                float v2 = __uint_as_float(r2.y), v3 = __uint_as_float(r3.y);
                float v4 = __uint_as_float(r4.y), v5 = __uint_as_float(r5.y);
                float v6 = __uint_as_float(r6.y), v7 = __uint_as_float(r7.y);
                ax += v0 * lo_f(u0); ay += v0 * hi_f(u0);
                bx += v1 * lo_f(u1); by += v1 * hi_f(u1);
                ax += v2 * lo_f(u2); ay += v2 * hi_f(u2);
                bx += v3 * lo_f(u3); by += v3 * hi_f(u3);
                ax += v4 * lo_f(u4); ay += v4 * hi_f(u4);
                bx += v5 * lo_f(u5); by += v5 * hi_f(u5);
                ax += v6 * lo_f(u6); ay += v6 * hi_f(u6);
                bx += v7 * lo_f(u7); by += v7 * hi_f(u7);
            }
            if (e < e1) {
                int last = e1 - 1;
                uint2 rr[8];
#pragma unroll
                for (int k = 0; k < 8; k++) {
                    int idx = e + k;
                    rr[k] = rec[(idx <= last) ? idx : last];
                }
                uint32_t uu[8];
#pragma unroll
                for (int k = 0; k < 8; k++) {
                    int c = min(max((int)rr[k].x, 0), N - 1);
                    uu[k] = egob[c * 64 + lane];
                }
#pragma unroll
                for (int k = 0; k < 8; k++) {
                    float v = (e + k < e1) ? __uint_as_float(rr[k].y) : 0.f;
                    if (k & 1) { bx += v * lo_f(uu[k]); by += v * hi_f(uu[k]); }
                    else       { ax += v * lo_f(uu[k]); ay += v * hi_f(uu[k]); }
                }
            }
            ax += bx; ay += by;
            float2 se = egf[node * 64 + lane];
            float2 sh = hh[node * 64 + lane];
            t1x = 0.9f * (se.x + ax) + 0.1f * sh.x;
            t1y = 0.9f * (se.y + ay) + 0.1f * sh.y;
            t2x = 0.9f * (se.x * ax) + 0.1f * sh.x;
            t2y = 0.9f * (se.y * ay) + 0.1f * sh.y;
        }
        int r = wave * 4 + i;
        s1d[r * (TSTR / 2) + lane] = pack2(t1x, t1y);
        s2d[r * (TSTR / 2) + lane] = pack2(t2x, t2y);
    }
    __syncthreads();
    gemm_phase(sT1, sT2, M1T, M2T, b1, b2, out, base, wave, lane, N);
}

// ======== fallback path (tiny ws): f32 side accumulated in-place in d_out ====
__global__ __launch_bounds__(256) void k_coo_side(
        const int* __restrict__ row, const int* __restrict__ col,
        const float* __restrict__ vals, const float2* __restrict__ egf,
        float* __restrict__ sideF, int E, int N) {
    long long t = (long long)blockIdx.x * blockDim.x + threadIdx.x;
    int e = (int)(t >> 6), l = (int)(t & 63);
    if (e >= E) return;
    int c = col[e]; c = min(max(c, 0), N - 1);
    int r = row[e]; r = min(max(r, 0), N - 1);
    float v = vals[e];
    float2 u = egf[c * 64 + l];
    atomicAdd(&sideF[r * D + 2 * l],     v * u.x);
    atomicAdd(&sideF[r * D + 2 * l + 1], v * u.y);
}

__global__ __launch_bounds__(256) void k_fused2(
        const float2* __restrict__ egf, const float2* __restrict__ hh,
        const uint16_t* __restrict__ M1T, const uint16_t* __restrict__ M2T,
        const float* __restrict__ b1, const float* __restrict__ b2,
        float* __restrict__ out, int N) {
    __shared__ __attribute__((aligned(16))) uint16_t sT1[16 * TSTR];
    __shared__ __attribute__((aligned(16))) uint16_t sT2[16 * TSTR];
    int tid = threadIdx.x;
    int wave = tid >> 6, lane = tid & 63;
    int base = blockIdx.x * 16;
    const float2* sd = (const float2*)out;
    uint32_t* s1d = (uint32_t*)sT1;
    uint32_t* s2d = (uint32_t*)sT2;

#pragma unroll
    for (int i = 0; i < 4; i++) {
        int node = base + wave * 4 + i;
        float t1x = 0.f, t1y = 0.f, t2x = 0.f, t2y = 0.f;
        if (node < N) {
            float2 us = sd[node * 64 + lane];
            float2 se = egf[node * 64 + lane];
            float2 sh = hh[node * 64 + lane];
            t1x = 0.9f * (se.x + us.x) + 0.1f * sh.x;
            t1y = 0.9f * (se.y + us.y) + 0.1f * sh.y;
            t2x = 0.9f * (se.x * us.x) + 0.1f * sh.x;
            t2y = 0.9f * (se.y * us.y) + 0.1f * sh.y;
        }
        int r = wave * 4 + i;
        s1d[r * (TSTR / 2) + lane] = pack2(t1x, t1y);
        s2d[r * (TSTR / 2) + lane] = pack2(t2x, t2y);
    }
    __syncthreads();
    gemm_phase(sT1, sT2, M1T, M2T, b1, b2, out, base, wave, lane, N);
}

extern "C" void kernel_launch(void* const* d_in, const int* in_sizes, int n_in,
                              void* d_out, int out_size, void* d_ws, size_t ws_size,
                              hipStream_t stream) {
    const float* ego  = (const float*)d_in[0];
    const float* h0   = (const float*)d_in[1];
    const float* vals = (const float*)d_in[2];
    const float* W    = (const float*)d_in[3];
    const float* w1   = (const float*)d_in[4];
    const float* b1   = (const float*)d_in[5];
    const float* w2   = (const float*)d_in[6];
    const float* b2   = (const float*)d_in[7];
    const int* row = (const int*)d_in[8];
    const int* col = (const int*)d_in[9];
    int N = in_sizes[0] / D;
    int E = in_sizes[2];

    int nbuck2 = (N + 255) >> 8;                  // 256-row buckets
    size_t cnt_elems = (size_t)nbuck2 * NWG2 + 2;
    if (cnt_elems < (size_t)MAXB * NWG + 1) cnt_elems = (size_t)MAXB * NWG + 1;

    char* p = (char*)d_ws;
    auto alloc = [&](size_t bytes) -> char* {
        char* q = p;
        p += (bytes + 511) & ~(size_t)511;
        return q;
    };
    uint16_t* M1T    = (uint16_t*)alloc(D * D * 2);
    uint16_t* M2T    = (uint16_t*)alloc(D * D * 2);
    uint32_t* egob   = (uint32_t*)alloc((size_t)N * 64 * 4);
    int*      deg    = (int*)alloc((size_t)N * 4);
    int*      rowptr = (int*)alloc((size_t)(N + 1) * 4);
    int*      wp     = (int*)alloc((size_t)N * 4);
    int*      bsum   = (int*)alloc(1024 * 4);
    int*      boff   = (int*)alloc(1024 * 4);      // doubles as bbase (<=513 ints)
    int*      cnt    = (int*)alloc(cnt_elems * 4);
    uint2*    rec    = (uint2*)alloc((size_t)E * 8);
    size_t need_fast = (size_t)(p - (char*)d_ws);

    if (ws_size >= need_fast) {
        int nquads = N * 32;
        bool bucket_ok = (nbuck2 <= MAXB2) && ((size_t)out_size * 4 >= (size_t)E * 8);
        if (bucket_ok) {
            // -- 4-dispatch bucketed build: front -> btop -> group -> place --
            int cvtB = (nquads + 255) / 256;
            k_front<<<64 + cvtB + NWG2, 256, 0, stream>>>(
                W, w1, w2, M1T, M2T,
                (const float4*)ego, (uint2*)egob, nquads,
                row, cnt, E, N, nbuck2, cvtB);
            k_btop<<<1, 512, 0, stream>>>(cnt, boff, nbuck2);
            k_group2<<<NWG2, 512, 0, stream>>>(row, col, vals, cnt, boff,
                                               (uint2*)d_out, E, N, nbuck2);
            k_place2<<<nbuck2, 512, 0, stream>>>((const uint2*)d_out, boff,
                                                 rowptr, rec, E, N, nbuck2);
        } else {
            // -- legacy atomic scatter (handles N > 131072) --
            k_prep<<<D, D, 0, stream>>>(W, w1, w2, M1T, M2T);
            k_cvt<<<(nquads + 255) / 256, 256, 0, stream>>>((const float4*)ego,
                                                            (uint2*)egob, nquads);
            hipMemsetAsync(deg, 0, (size_t)N * 4, stream);
            int nb = (N + 1023) / 1024;
            k_hist<<<(E + 255) / 256, 256, 0, stream>>>(row, deg, E, N);
            k_scan1<<<nb, 1024, 0, stream>>>(deg, rowptr, bsum, N);
            k_scan2<<<1, 1, 0, stream>>>(bsum, boff, nb, rowptr, N);
            k_scan3<<<nb, 1024, 0, stream>>>(deg, boff, rowptr, wp, N);
            k_scatter<<<(E + 255) / 256, 256, 0, stream>>>(row, col, vals, wp,
                                                           rec, E, N);
        }
        int nblocks = (N + 15) / 16;
        k_fused<<<nblocks, 256, 0, stream>>>(rowptr, rec, egob,
                                             (const float2*)ego, (const float2*)h0,
                                             M1T, M2T, b1, b2, (float*)d_out, N);
    } else {
        k_prep<<<D, D, 0, stream>>>(W, w1, w2, M1T, M2T);
        hipMemsetAsync(d_out, 0, (size_t)out_size * 4, stream);
        long long tthr = (long long)E * 64;
        int blocks = (int)((tthr + 255) / 256);
        k_coo_side<<<blocks, 256, 0, stream>>>(row, col, vals, (const float2*)ego,
                                               (float*)d_out, E, N);
        int nblocks = (N + 15) / 16;
        k_fused2<<<nblocks, 256, 0, stream>>>((const float2*)ego, (const float2*)h0,
                                              M1T, M2T, b1, b2, (float*)d_out, N);
    }
}

// Round 8
// 448.898 us; speedup vs baseline: 1.7079x; 1.0595x over previous
//
#include <hip/hip_runtime.h>
#include <stdint.h>

#define D 128
#define BETA 0.40546510810816444f   // log(1.5)
#define TSTR 136                     // padded LDS row stride (bf16 elems)

#define NWG  128                     // legacy fallback bucket passes
#define MAXB 256                     // legacy: 512-row buckets, N <= 131072

#define NWG2 256                     // group/bhist workgroups (full machine)
#define BROWS 256                    // rows per bucket
#define MAXB2 512                    // max buckets: N <= 131072

typedef __bf16 bf16x8 __attribute__((ext_vector_type(8)));
typedef float f32x4 __attribute__((ext_vector_type(4)));

__device__ __forceinline__ uint16_t f2bf(float f) {
    union { float f; uint32_t i; } x; x.f = f;
    uint32_t r = (x.i + 0x7fffu + ((x.i >> 16) & 1u)) >> 16;
    return (uint16_t)r;
}
__device__ __forceinline__ float lo_f(uint32_t u) { return __uint_as_float(u << 16); }
__device__ __forceinline__ float hi_f(uint32_t u) { return __uint_as_float(u & 0xffff0000u); }
__device__ __forceinline__ uint32_t pack2(float x, float y) {
    return (uint32_t)f2bf(x) | ((uint32_t)f2bf(y) << 16);
}

// ================= legacy CSR build (N > 131072 fallback) ==================
__global__ void k_hist(const int* __restrict__ row, int* __restrict__ deg, int E, int N) {
    int e = blockIdx.x * blockDim.x + threadIdx.x;
    if (e < E) {
        int r = row[e]; r = min(max(r, 0), N - 1);
        atomicAdd(&deg[r], 1);
    }
}

__global__ void k_scan1(const int* __restrict__ deg, int* __restrict__ inc,
                        int* __restrict__ bsum, int n) {
    __shared__ int s[1024];
    int i = blockIdx.x * 1024 + threadIdx.x;
    int v = (i < n) ? deg[i] : 0;
    s[threadIdx.x] = v;
    __syncthreads();
    for (int d = 1; d < 1024; d <<= 1) {
        int t = (threadIdx.x >= (unsigned)d) ? s[threadIdx.x - d] : 0;
        __syncthreads();
        s[threadIdx.x] += t;
        __syncthreads();
    }
    if (i < n) inc[i] = s[threadIdx.x];
    if (threadIdx.x == 1023) bsum[blockIdx.x] = s[1023];
}

__global__ void k_scan2(const int* __restrict__ bsum, int* __restrict__ boff,
                        int nb, int* __restrict__ rowptr, int N) {
    int run = 0;
    for (int b = 0; b < nb; b++) { boff[b] = run; run += bsum[b]; }
    rowptr[N] = run;
}

__global__ void k_scan3(const int* __restrict__ deg, const int* __restrict__ boff,
                        int* __restrict__ rowptr, int* __restrict__ wp, int n) {
    int i = blockIdx.x * 1024 + threadIdx.x;
    if (i < n) {
        int ex = rowptr[i] - deg[i] + boff[blockIdx.x];
        rowptr[i] = ex;
        wp[i] = ex;
    }
}

__global__ void k_scatter(const int* __restrict__ row, const int* __restrict__ col,
                          const float* __restrict__ vals, int* __restrict__ wp,
                          uint2* __restrict__ rec, int E, int N) {
    int e = blockIdx.x * blockDim.x + threadIdx.x;
    if (e < E) {
        int r = row[e]; r = min(max(r, 0), N - 1);
        int pos = atomicAdd(&wp[r], 1);
        pos = min(max(pos, 0), E - 1);
        uint2 rv;
        rv.x = (uint32_t)col[e];
        rv.y = __float_as_uint(vals[e]);
        rec[pos] = rv;
    }
}

// ======== standalone prep/cvt (fallback paths) ========
__global__ void k_cvt(const float4* __restrict__ src, uint2* __restrict__ dst, int n) {
    int i = blockIdx.x * blockDim.x + threadIdx.x;
    if (i < n) {
        float4 v = src[i];
        uint2 o; o.x = pack2(v.x, v.y); o.y = pack2(v.z, v.w);
        dst[i] = o;
    }
}

__global__ void k_prep(const float* __restrict__ W, const float* __restrict__ w1,
                       const float* __restrict__ w2, uint16_t* __restrict__ M1T,
                       uint16_t* __restrict__ M2T) {
    int k = blockIdx.x, n = threadIdx.x;
    __shared__ float imrow[D];
    imrow[n] = (1.0f - BETA) + BETA * W[k * D + n];
    __syncthreads();
    float s1 = 0.f, s2 = 0.f;
    for (int j = 0; j < D; j++) {
        float im = imrow[j];
        s1 += im * w1[j * D + n];
        s2 += im * w2[j * D + n];
    }
    M1T[n * D + k] = f2bf(s1);
    M2T[n * D + k] = f2bf(s2);
}

// ============ fused front: prep (0..63) + cvt + bhist (256 WGs) =============
__global__ __launch_bounds__(256) void k_front(
        const float* __restrict__ W, const float* __restrict__ w1,
        const float* __restrict__ w2, uint16_t* __restrict__ M1T,
        uint16_t* __restrict__ M2T,
        const float4* __restrict__ egoq, uint2* __restrict__ egobq, int nquads,
        const int* __restrict__ row, int* __restrict__ cnt,
        int E, int N, int nbuck, int cvtB) {
    __shared__ int h[MAXB2];
    __shared__ float imrow[2][D];
    int tid = threadIdx.x;
    int bid = blockIdx.x;

    if (bid < 64) {
        // ---- prep role: 2 k-rows per block ----
        int half = tid >> 7;
        int n = tid & 127;
        int k = bid * 2 + half;
        imrow[half][n] = (1.0f - BETA) + BETA * W[k * D + n];
        __syncthreads();
        float s1 = 0.f, s2 = 0.f;
        for (int j = 0; j < D; j++) {
            float im = imrow[half][j];
            s1 += im * w1[j * D + n];
            s2 += im * w2[j * D + n];
        }
        M1T[n * D + k] = f2bf(s1);
        M2T[n * D + k] = f2bf(s2);
        return;
    }
    if (bid < 64 + cvtB) {
        // ---- cvt role ----
        int i = (bid - 64) * 256 + tid;
        if (i < nquads) {
            float4 v = egoq[i];
            uint2 o; o.x = pack2(v.x, v.y); o.y = pack2(v.z, v.w);
            egobq[i] = o;
        }
        return;
    }
    // ---- bhist role (256 WGs, 256-row buckets) ----
    int w = bid - 64 - cvtB;
    for (int b = tid; b < nbuck; b += 256) h[b] = 0;
    __syncthreads();
    int chunk = (E + NWG2 - 1) / NWG2;
    int beg = w * chunk, end = min(beg + chunk, E);
    for (int e = beg + tid; e < end; e += 256) {
        int r = row[e]; r = min(max(r, 0), N - 1);
        atomicAdd(&h[r >> 8], 1);
    }
    __syncthreads();
    for (int b = tid; b < nbuck; b += 256) cnt[b * NWG2 + w] = h[b];
}

// ============ group: 256 WGs x 512 thr; per-WG private bucket segments ======
// Prelude: every block redundantly computes the bucket-total exclusive scan
// from the L2-hot cnt matrix (deterministic across blocks; replaces the
// separate k_btop dispatch). Block 0 publishes bbase for k_place2. Then
// lbase[b] = bbase[b] + sum_{w'<w} cnt[b][w'].
// Record: x = (row&255)<<17 | col (needs N <= 131072).
__global__ __launch_bounds__(512) void k_group2(const int* __restrict__ row,
                                                const int* __restrict__ col,
                                                const float* __restrict__ vals,
                                                const int* __restrict__ cnt,
                                                int* __restrict__ bbase,
                                                uint2* __restrict__ grouped,
                                                int E, int N, int nbuck) {
    __shared__ int s[512];
    __shared__ int bb[MAXB2 + 1];
    __shared__ int lbase[MAXB2];
    __shared__ int lcnt[MAXB2];
    int t = threadIdx.x;
    int w = blockIdx.x;

    // ---- bucket totals + 512-wide exclusive scan ----
    int tot = 0;
    if (t < nbuck) {
        const int4* p4 = (const int4*)(cnt + t * NWG2);
#pragma unroll 4
        for (int i2 = 0; i2 < NWG2 / 4; i2++) {
            int4 v = p4[i2];
            tot += v.x + v.y + v.z + v.w;
        }
    }
    s[t] = tot;
    __syncthreads();
    for (int d = 1; d < 512; d <<= 1) {
        int x = (t >= d) ? s[t - d] : 0;
        __syncthreads();
        s[t] += x;
        __syncthreads();
    }
    if (t < nbuck) bb[t] = s[t] - tot;
    if (t == 511) bb[nbuck] = s[511];
    __syncthreads();
    if (w == 0) {
        for (int b = t; b <= nbuck; b += 512) bbase[b] = bb[b];
    }

    // ---- per-WG private segment bases ----
    for (int b = t; b < nbuck; b += 512) {
        const int* cr = cnt + b * NWG2;
        int off = bb[b];
        for (int w2 = 0; w2 < w; w2++) off += cr[w2];
        lbase[b] = off;
        lcnt[b] = 0;
    }
    __syncthreads();
    int chunk = (E + NWG2 - 1) / NWG2;
    int beg = w * chunk, end = min(beg + chunk, E);
    for (int e = beg + t; e < end; e += 512) {
        int r = row[e]; r = min(max(r, 0), N - 1);
        int c = col[e]; c = min(max(c, 0), N - 1);
        int b = r >> 8;
        int lp = atomicAdd(&lcnt[b], 1);
        int pos = lbase[b] + lp;
        pos = min(max(pos, 0), E - 1);
        uint2 g;
        g.x = ((uint32_t)(r & 255) << 17) | (uint32_t)c;
        g.y = __float_as_uint(vals[e]);
        grouped[pos] = g;
    }
}

// ============ place: one block per 256-row bucket (~391 blocks) =============
__global__ __launch_bounds__(512) void k_place2(const uint2* __restrict__ grouped,
                                                const int* __restrict__ bbase,
                                                int* __restrict__ rowptr,
                                                uint2* __restrict__ rec,
                                                int E, int N, int nbuck) {
    __shared__ int lh[BROWS];
    __shared__ int lcc[BROWS];
    __shared__ int ps[BROWS];
    int b = blockIdx.x;
    int t = threadIdx.x;
    int pb = bbase[b], pe = bbase[b + 1];
    if (t < BROWS) { lh[t] = 0; lcc[t] = 0; }
    __syncthreads();
    for (int i = pb + t; i < pe; i += 512)
        atomicAdd(&lh[grouped[i].x >> 17], 1);
    __syncthreads();
    int v = (t < BROWS) ? lh[t] : 0;
    if (t < BROWS) ps[t] = v;
    __syncthreads();
    for (int d = 1; d < BROWS; d <<= 1) {
        int x = (t < BROWS && t >= d) ? ps[t - d] : 0;
        __syncthreads();
        if (t < BROWS) ps[t] += x;
        __syncthreads();
    }
    if (t < BROWS) lh[t] = ps[t] - v;           // exclusive row offsets
    __syncthreads();
    int rbase = b << 8;
    if (t < BROWS) {
        int r = rbase + t;
        if (r < N) rowptr[r] = pb + lh[t];
    }
    if (b == nbuck - 1 && t == 0) rowptr[N] = E;
    for (int i = pb + t; i < pe; i += 512) {
        uint2 g = grouped[i];
        int rl = (int)(g.x >> 17);
        int lp = atomicAdd(&lcc[rl], 1);
        int pos = pb + lh[rl] + lp;
        pos = min(max(pos, 0), E - 1);
        uint2 rv; rv.x = g.x & 0x1FFFFu; rv.y = g.y;
        rec[pos] = rv;
    }
}

// ======== shared phase-2: dual MFMA GEMM + leaky-relu epilogue (f32 out) ====
__device__ __forceinline__ void gemm_phase(
        const uint16_t* sT1, const uint16_t* sT2,
        const uint16_t* __restrict__ M1T, const uint16_t* __restrict__ M2T,
        const float* __restrict__ b1, const float* __restrict__ b2,
        float* __restrict__ out, int base, int wave, int lane, int N) {
    int l15 = lane & 15, quad = lane >> 4;
#pragma unroll
    for (int t = 0; t < 2; t++) {
        int tn = wave * 2 + t;
        f32x4 acc1 = {0.f, 0.f, 0.f, 0.f}, acc2 = {0.f, 0.f, 0.f, 0.f};
#pragma unroll
        for (int kb = 0; kb < 4; kb++) {
            int ko = kb * 32 + quad * 8;
            bf16x8 a1 = *(const bf16x8*)(sT1 + l15 * TSTR + ko);
            bf16x8 a2 = *(const bf16x8*)(sT2 + l15 * TSTR + ko);
            bf16x8 bb1 = *(const bf16x8*)(M1T + (tn * 16 + l15) * D + ko);
            bf16x8 bb2 = *(const bf16x8*)(M2T + (tn * 16 + l15) * D + ko);
            acc1 = __builtin_amdgcn_mfma_f32_16x16x32_bf16(a1, bb1, acc1, 0, 0, 0);
            acc2 = __builtin_amdgcn_mfma_f32_16x16x32_bf16(a2, bb2, acc2, 0, 0, 0);
        }
        int colo = tn * 16 + l15;
        float bbias1 = b1[colo], bbias2 = b2[colo];
#pragma unroll
        for (int r = 0; r < 4; r++) {
            int rowi = base + quad * 4 + r;
            if (rowi < N) {
                float v1 = acc1[r] + bbias1;
                v1 = (v1 >= 0.f) ? v1 : 0.01f * v1;
                float v2 = acc2[r] + bbias2;
                v2 = (v2 >= 0.f) ? v2 : 0.01f * v2;
                out[(size_t)rowi * D + colo] = v1 + v2;   // FLOAT32 output
            }
        }
    }
}

// ======== fast path: CSR gather (bf16 ego copy) -> LDS -> GEMM ========
// node / rowptr / rec are wave-uniform: readfirstlane forces them onto the
// scalar path (s_load records, s_min/s_max clamps, saddr-form gathers) so
// the VMEM queue carries only the 8 outstanding 256B gathers per wave.
__global__ __launch_bounds__(256) void k_fused(
        const int* __restrict__ rowptr, const uint2* __restrict__ rec,
        const uint32_t* __restrict__ egob,
        const float2* __restrict__ egf, const float2* __restrict__ hh,
        const uint16_t* __restrict__ M1T, const uint16_t* __restrict__ M2T,
        const float* __restrict__ b1, const float* __restrict__ b2,
        float* __restrict__ out, int N) {
    __shared__ __attribute__((aligned(16))) uint16_t sT1[16 * TSTR];
    __shared__ __attribute__((aligned(16))) uint16_t sT2[16 * TSTR];
    int tid = threadIdx.x;
    int wave = tid >> 6, lane = tid & 63;
    int base = blockIdx.x * 16;
    uint32_t* s1d = (uint32_t*)sT1;
    uint32_t* s2d = (uint32_t*)sT2;

#pragma unroll
    for (int i = 0; i < 4; i++) {
        int node = __builtin_amdgcn_readfirstlane(base + wave * 4 + i);
        float t1x = 0.f, t1y = 0.f, t2x = 0.f, t2y = 0.f;
        if (node < N) {
            int e0 = rowptr[node], e1 = rowptr[node + 1];   // s_load
            float ax = 0.f, ay = 0.f, bx = 0.f, by = 0.f;
            int e = e0;
            for (; e + 8 <= e1; e += 8) {
                uint2 r0 = rec[e + 0], r1 = rec[e + 1], r2 = rec[e + 2], r3 = rec[e + 3];
                uint2 r4 = rec[e + 4], r5 = rec[e + 5], r6 = rec[e + 6], r7 = rec[e + 7];
                int c0 = min(max((int)r0.x, 0), N - 1);
                int c1 = min(max((int)r1.x, 0), N - 1);
                int c2 = min(max((int)r2.x, 0), N - 1);
                int c3 = min(max((int)r3.x, 0), N - 1);
                int c4 = min(max((int)r4.x, 0), N - 1);
                int c5 = min(max((int)r5.x, 0), N - 1);
                int c6 = min(max((int)r6.x, 0), N - 1);
                int c7 = min(max((int)r7.x, 0), N - 1);
                uint32_t u0 = egob[c0 * 64 + lane];
                uint32_t u1 = egob[c1 * 64 + lane];
                uint32_t u2 = egob[c2 * 64 + lane];
                uint32_t u3 = egob[c3 * 64 + lane];
                uint32_t u4 = egob[c4 * 64 + lane];
                uint32_t u5 = egob[c5 * 64 + lane];
                uint32_t u6 = egob[c6 * 64 + lane];
                uint32_t u7 = egob[c7 * 64 + lane];
                float v0 = __uint_as_float(r0.y), v1 = __uint_as_float(r1.y);
                float v2 = __uint_as_float(r2.y), v3 = __uint_as_float(r3.y);
                float v4 = __uint_as_float(r4.y), v5 = __uint_as_float(r5.y);
                float v6 = __uint_as_float(r6.y), v7 = __uint_as_float(r7.y);
                ax += v0 * lo_f(u0); ay += v0 * hi_f(u0);
                bx += v1 * lo_f(u1); by += v1 * hi_f(u1);
                ax += v2 * lo_f(u2); ay += v2 * hi_f(u2);
                bx += v3 * lo_f(u3); by += v3 * hi_f(u3);
                ax += v4 * lo_f(u4); ay += v4 * hi_f(u4);
                bx += v5 * lo_f(u5); by += v5 * hi_f(u5);
                ax += v6 * lo_f(u6); ay += v6 * hi_f(u6);
                bx += v7 * lo_f(u7); by += v7 * hi_f(u7);
            }
            if (e < e1) {
                // single masked 8-wide tail: OOB slots re-load the last record
                // (scalar-cache-hot) with val forced to 0.
                int last = e1 - 1;
                uint2 rr[8];
#pragma unroll
                for (int k = 0; k < 8; k++) {
                    int idx = e + k;
                    rr[k] = rec[(idx <= last) ? idx : last];
                }
                uint32_t uu[8];
#pragma unroll
                for (int k = 0; k < 8; k++) {
                    int c = min(max((int)rr[k].x, 0), N - 1);
                    uu[k] = egob[c * 64 + lane];
                }
#pragma unroll
                for (int k = 0; k < 8; k++) {
                    float v = (e + k < e1) ? __uint_as_float(rr[k].y) : 0.f;
                    if (k & 1) { bx += v * lo_f(uu[k]); by += v * hi_f(uu[k]); }
                    else       { ax += v * lo_f(uu[k]); ay += v * hi_f(uu[k]); }
                }
            }
            ax += bx; ay += by;
            float2 se = egf[node * 64 + lane];
            float2 sh = hh[node * 64 + lane];
            t1x = 0.9f * (se.x + ax) + 0.1f * sh.x;
            t1y = 0.9f * (se.y + ay) + 0.1f * sh.y;
            t2x = 0.9f * (se.x * ax) + 0.1f * sh.x;
            t2y = 0.9f * (se.y * ay) + 0.1f * sh.y;
        }
        int r = wave * 4 + i;
        s1d[r * (TSTR / 2) + lane] = pack2(t1x, t1y);
        s2d[r * (TSTR / 2) + lane] = pack2(t2x, t2y);
    }
    __syncthreads();
    gemm_phase(sT1, sT2, M1T, M2T, b1, b2, out, base, wave, lane, N);
}

// ======== fallback path (tiny ws): f32 side accumulated in-place in d_out ====
__global__ __launch_bounds__(256) void k_coo_side(
        const int* __restrict__ row, const int* __restrict__ col,
        const float* __restrict__ vals, const float2* __restrict__ egf,
        float* __restrict__ sideF, int E, int N) {
    long long t = (long long)blockIdx.x * blockDim.x + threadIdx.x;
    int e = (int)(t >> 6), l = (int)(t & 63);
    if (e >= E) return;
    int c = col[e]; c = min(max(c, 0), N - 1);
    int r = row[e]; r = min(max(r, 0), N - 1);
    float v = vals[e];
    float2 u = egf[c * 64 + l];
    atomicAdd(&sideF[r * D + 2 * l],     v * u.x);
    atomicAdd(&sideF[r * D + 2 * l + 1], v * u.y);
}

__global__ __launch_bounds__(256) void k_fused2(
        const float2* __restrict__ egf, const float2* __restrict__ hh,
        const uint16_t* __restrict__ M1T, const uint16_t* __restrict__ M2T,
        const float* __restrict__ b1, const float* __restrict__ b2,
        float* __restrict__ out, int N) {
    __shared__ __attribute__((aligned(16))) uint16_t sT1[16 * TSTR];
    __shared__ __attribute__((aligned(16))) uint16_t sT2[16 * TSTR];
    int tid = threadIdx.x;
    int wave = tid >> 6, lane = tid & 63;
    int base = blockIdx.x * 16;
    const float2* sd = (const float2*)out;
    uint32_t* s1d = (uint32_t*)sT1;
    uint32_t* s2d = (uint32_t*)sT2;

#pragma unroll
    for (int i = 0; i < 4; i++) {
        int node = base + wave * 4 + i;
        float t1x = 0.f, t1y = 0.f, t2x = 0.f, t2y = 0.f;
        if (node < N) {
            float2 us = sd[node * 64 + lane];
            float2 se = egf[node * 64 + lane];
            float2 sh = hh[node * 64 + lane];
            t1x = 0.9f * (se.x + us.x) + 0.1f * sh.x;
            t1y = 0.9f * (se.y + us.y) + 0.1f * sh.y;
            t2x = 0.9f * (se.x * us.x) + 0.1f * sh.x;
            t2y = 0.9f * (se.y * us.y) + 0.1f * sh.y;
        }
        int r = wave * 4 + i;
        s1d[r * (TSTR / 2) + lane] = pack2(t1x, t1y);
        s2d[r * (TSTR / 2) + lane] = pack2(t2x, t2y);
    }
    __syncthreads();
    gemm_phase(sT1, sT2, M1T, M2T, b1, b2, out, base, wave, lane, N);
}

extern "C" void kernel_launch(void* const* d_in, const int* in_sizes, int n_in,
                              void* d_out, int out_size, void* d_ws, size_t ws_size,
                              hipStream_t stream) {
    const float* ego  = (const float*)d_in[0];
    const float* h0   = (const float*)d_in[1];
    const float* vals = (const float*)d_in[2];
    const float* W    = (const float*)d_in[3];
    const float* w1   = (const float*)d_in[4];
    const float* b1   = (const float*)d_in[5];
    const float* w2   = (const float*)d_in[6];
    const float* b2   = (const float*)d_in[7];
    const int* row = (const int*)d_in[8];
    const int* col = (const int*)d_in[9];
    int N = in_sizes[0] / D;
    int E = in_sizes[2];

    int nbuck2 = (N + 255) >> 8;                  // 256-row buckets
    size_t cnt_elems = (size_t)nbuck2 * NWG2 + 2;
    if (cnt_elems < (size_t)MAXB * NWG + 1) cnt_elems = (size_t)MAXB * NWG + 1;

    char* p = (char*)d_ws;
    auto alloc = [&](size_t bytes) -> char* {
        char* q = p;
        p += (bytes + 511) & ~(size_t)511;
        return q;
    };
    uint16_t* M1T    = (uint16_t*)alloc(D * D * 2);
    uint16_t* M2T    = (uint16_t*)alloc(D * D * 2);
    uint32_t* egob   = (uint32_t*)alloc((size_t)N * 64 * 4);
    int*      deg    = (int*)alloc((size_t)N * 4);
    int*      rowptr = (int*)alloc((size_t)(N + 1) * 4);
    int*      wp     = (int*)alloc((size_t)N * 4);
    int*      bsum   = (int*)alloc(1024 * 4);
    int*      boff   = (int*)alloc(1024 * 4);      // doubles as bbase (<=513 ints)
    int*      cnt    = (int*)alloc(cnt_elems * 4);
    uint2*    rec    = (uint2*)alloc((size_t)E * 8);
    size_t need_fast = (size_t)(p - (char*)d_ws);

    if (ws_size >= need_fast) {
        int nquads = N * 32;
        bool bucket_ok = (nbuck2 <= MAXB2) && ((size_t)out_size * 4 >= (size_t)E * 8);
        if (bucket_ok) {
            // -- 3-dispatch bucketed build: front -> group(+scan) -> place --
            int cvtB = (nquads + 255) / 256;
            k_front<<<64 + cvtB + NWG2, 256, 0, stream>>>(
                W, w1, w2, M1T, M2T,
                (const float4*)ego, (uint2*)egob, nquads,
                row, cnt, E, N, nbuck2, cvtB);
            k_group2<<<NWG2, 512, 0, stream>>>(row, col, vals, cnt, boff,
                                               (uint2*)d_out, E, N, nbuck2);
            k_place2<<<nbuck2, 512, 0, stream>>>((const uint2*)d_out, boff,
                                                 rowptr, rec, E, N, nbuck2);
        } else {
            // -- legacy atomic scatter (handles N > 131072) --
            k_prep<<<D, D, 0, stream>>>(W, w1, w2, M1T, M2T);
            k_cvt<<<(nquads + 255) / 256, 256, 0, stream>>>((const float4*)ego,
                                                            (uint2*)egob, nquads);
            hipMemsetAsync(deg, 0, (size_t)N * 4, stream);
            int nb = (N + 1023) / 1024;
            k_hist<<<(E + 255) / 256, 256, 0, stream>>>(row, deg, E, N);
            k_scan1<<<nb, 1024, 0, stream>>>(deg, rowptr, bsum, N);
            k_scan2<<<1, 1, 0, stream>>>(bsum, boff, nb, rowptr, N);
            k_scan3<<<nb, 1024, 0, stream>>>(deg, boff, rowptr, wp, N);
            k_scatter<<<(E + 255) / 256, 256, 0, stream>>>(row, col, vals, wp,
                                                           rec, E, N);
        }
        int nblocks = (N + 15) / 16;
        k_fused<<<nblocks, 256, 0, stream>>>(rowptr, rec, egob,
                                             (const float2*)ego, (const float2*)h0,
                                             M1T, M2T, b1, b2, (float*)d_out, N);
    } else {
        k_prep<<<D, D, 0, stream>>>(W, w1, w2, M1T, M2T);
        hipMemsetAsync(d_out, 0, (size_t)out_size * 4, stream);
        long long tthr = (long long)E * 64;
        int blocks = (int)((tthr + 255) / 256);
        k_coo_side<<<blocks, 256, 0, stream>>>(row, col, vals, (const float2*)ego,
                                               (float*)d_out, E, N);
        int nblocks = (N + 15) / 16;
        k_fused2<<<nblocks, 256, 0, stream>>>((const float2*)ego, (const float2*)h0,
                                              M1T, M2T, b1, b2, (float*)d_out, N);
    }
}